// Round 9
// baseline (1228.897 us; speedup 1.0000x reference)
//
#include <hip/hip_runtime.h>
#include <hip/hip_bf16.h>

typedef __attribute__((ext_vector_type(8))) short s16x8;
typedef __attribute__((ext_vector_type(4))) float f32x4;

#define MFMA_B16(a, b, c) __builtin_amdgcn_mfma_f32_16x16x32_bf16((a), (b), (c), 0, 0, 0)

static __device__ __forceinline__ short f2bf(float f) {
    __hip_bfloat16 h = __float2bfloat16(f);
    return __builtin_bit_cast(short, h);
}
static __device__ __forceinline__ float rcp_f(float x) {
    return __builtin_amdgcn_rcpf(x);
}

// pre-pass: X fp32 -> bf16 in workspace
__global__ void xcvt_kernel(const float* __restrict__ X, short* __restrict__ Xb, int n) {
    int i = (blockIdx.x * 256 + threadIdx.x) * 4;
    if (i < n) {
        float4 v = *(const float4*)(X + i);
        short4 o;
        o.x = f2bf(v.x); o.y = f2bf(v.y); o.z = f2bf(v.z); o.w = f2bf(v.w);
        *(short4*)(Xb + i) = o;
    }
}

// Ensemble LSTM, batch-split-8: WG = (series n, 4 batches). 256 WGs = 256 CUs.
// R18 = symmetric pred partials on the R16 base. Eliminated as critical path:
// MFMA issue (R16), LDS bytes/conflicts (R11/R14), schedule order (R10), C-chain
// depth (R17 - MFMA C->C is pipe-forwarded, moving the sum to VALU adds HURT),
// occupancy (R12/R13), launch count (R15). Remaining attackable term: barrier
// pacing - one wave per step ran 4 extra pred MFMAs (+~80cy straggle) and a
// divergent branch; the WG barrier re-paid that EVERY step. Now: pred dot split
// into 4 kt-partials, 1 MFMA per wave per step (kt=w&3; waves w,w+4 duplicate
// harmlessly - identical inputs, identical bytes to same LDS addr). Uniform 17
// MFMA/wave/step, no rotation branch. Partials in 4x8KB LDS slabs; flush sums
// + bias (f32 reassociation ~1e-7 << 3.9e-3 tol). Bp 4 frags -> 1 (-12 VGPR).
// Journal:
//   R5/R6 x-pair packing     -> +15 us   R7 asm barrier -> +21 us
//   R8 LDS atomicAdd pred    -> +834 us  R10 acc ping-pong -> neutral
//   R11 masked compact LDS   -> +105 us  R12 bounds(512,4) -> +3200 us (spill)
//   R13 grid 512             -> 2x       R14 compact bcast h -> +11 us
//   R15 fused xcvt           -> neutral (gap = harness overhead)
//   R16 4-step-grouped xproj -> -6 us (355.7 best; issue NOT the bottleneck)
//   R17 depth-1 gate chains  -> +33 us (C-chain is free; VALU add tree is not)
template<bool BF16X>
__global__ __launch_bounds__(512, 2)
void clstm_kernel(const float* __restrict__ X,
                  const short* __restrict__ Xb,
                  const float* __restrict__ W_ih,
                  const float* __restrict__ W_hh,
                  const float* __restrict__ b_ih,
                  const float* __restrict__ b_hh,
                  const float* __restrict__ W_out,
                  const float* __restrict__ b_out,
                  float* __restrict__ out)
{
    constexpr int B = 32, T = 512, N = 32, H = 128, G = 512;  // G = 4H
    constexpr int HT_OFF = B * T * N;
    constexpr int CT_OFF = HT_OFF + N * B * H;
    constexpr int PRED_OFF = 8192;     // 4 x 8KB pred partial slabs
    constexpr float C1 = 1.4426950408889634f;   // log2(e)

    __shared__ __align__(16) unsigned char smem[8192 + 32768];

    const int tid  = threadIdx.x;
    const int w    = tid >> 6;   // wave 0..7
    const int L    = tid & 63;
    const int col  = L & 15;
    const int quad = L >> 4;
    const int n    = blockIdx.x & 31;   // series
    const int bgrp = blockIdx.x >> 5;   // batch group (4 batches)
    const int pkt  = w & 3;             // this wave's pred kt-partial

    // ---- loop-invariant weight fragments (fp32 -> bf16, once) ----
    s16x8 Bh[4][4];  // [gate tt][kt]
    s16x8 Bx[4];     // [gate tt]  k = input p 0..31
    f32x4 biasv[4];  // bias broadcast (group-top C operand)
#pragma unroll
    for (int tt = 0; tt < 4; ++tt) {
        const int g = (w + 8 * tt) * 16 + col;
        const float* whr = W_hh + ((size_t)n * G + g) * H + quad * 8;
#pragma unroll
        for (int kt = 0; kt < 4; ++kt) {
            const float* p = whr + kt * 32;
#pragma unroll
            for (int jj = 0; jj < 8; ++jj) Bh[tt][kt][jj] = f2bf(p[jj]);
        }
        const float* wir = W_ih + ((size_t)n * G + g) * N + quad * 8;
#pragma unroll
        for (int jj = 0; jj < 8; ++jj) Bx[tt][jj] = f2bf(wir[jj]);
        const float bb = b_ih[n * G + g] + b_hh[n * G + g];
        biasv[tt] = (f32x4){bb, bb, bb, bb};
    }

    // ---- pred tile: ONE kt-slice per wave; B col 0 = W_out slice ----
    s16x8 Bp1;
    const float bo = b_out[n];
    const f32x4 z4 = (f32x4){0.f, 0.f, 0.f, 0.f};
    {
        const float* wp = W_out + n * H + pkt * 32 + quad * 8;
#pragma unroll
        for (int jj = 0; jj < 8; ++jj)
            Bp1[jj] = (col == 0) ? f2bf(wp[jj]) : (short)0;
    }

    // ---- h writer offset: cell (batch=quad -> m=4*quad, j=w*16+col) ----
    int wboff;
    {
        const int j = w * 16 + col;
        wboff = (j >> 5) * 1024 + (((((j >> 3) & 3) << 4) | (quad << 2)) * 16) + (j & 7) * 2;
    }

    // ---- grouped x loader: ALL lanes; A row = 4*batch + tsub ----
    const int xb = bgrp * 4 + (col >> 2);
    const int ts = col & 3;
    const float* xp  = X + ((size_t)xb * T + ts) * N + quad * 8;
    const short* xbp = BF16X ? (Xb + ((size_t)xb * T + ts) * N + quad * 8) : nullptr;

    auto loadxg = [&](int tg) -> s16x8 {
        if constexpr (BF16X) {
            return *(const s16x8*)(xbp + (size_t)tg * N);
        } else {
            float4 lo = *(const float4*)(xp + (size_t)tg * N);
            float4 hi = *(const float4*)(xp + (size_t)tg * N + 4);
            s16x8 r;
            r[0] = f2bf(lo.x); r[1] = f2bf(lo.y); r[2] = f2bf(lo.z); r[3] = f2bf(lo.w);
            r[4] = f2bf(hi.x); r[5] = f2bf(hi.y); r[6] = f2bf(hi.z); r[7] = f2bf(hi.w);
            return r;
        }
    };

    // zero h frag dbuf (pad rows must stay 0); pred slabs fully written before read
    *(float4*)(smem + tid * 16) = make_float4(0.f, 0.f, 0.f, 0.f);

    float cst = 0.f, hlast = 0.f;

    // prologue: x for group 0 and prefetch for group 1
    s16x8 xgC = loadxg(0);
    s16x8 xgN = loadxg(4);

    __syncthreads();

// Per step: Af from LDS; C operand = splat of acc4[tt][J]; gates accumulate
// in the MFMA pipe (C->C forwarded, R17 lesson). Pred: 1 partial MFMA per wave
// (symmetric, no straggler). Epilogue reads cur[tt][0].
#define STEP(P, TCUR, J)                                                            \
    {                                                                               \
        const unsigned char* rb = smem + (P) * 4096;                                \
        s16x8 Af[4];                                                                \
        _Pragma("unroll")                                                           \
        for (int kt = 0; kt < 4; ++kt)                                              \
            Af[kt] = *(const s16x8*)(rb + kt * 1024 + L * 16);                      \
        f32x4 cur[4];                                                               \
        _Pragma("unroll")                                                           \
        for (int tt = 0; tt < 4; ++tt) {                                            \
            const float a = acc4[tt][(J)];                                          \
            cur[tt] = (f32x4){a, a, a, a};                                          \
        }                                                                           \
        _Pragma("unroll")                                                           \
        for (int kt = 0; kt < 4; ++kt) {                                            \
            _Pragma("unroll")                                                       \
            for (int tt = 0; tt < 4; ++tt)                                          \
                cur[tt] = MFMA_B16(Af[kt], Bh[tt][kt], cur[tt]);                    \
        }                                                                           \
        {                                                                           \
            f32x4 pacc = MFMA_B16(Af[pkt], Bp1, z4);                                \
            if ((TCUR) > 0 && col == 0)                                             \
                *(float*)(smem + PRED_OFF + pkt * 8192 +                            \
                          ((quad << 9) + (TCUR) - 1) * 4) = pacc[0];                \
        }                                                                           \
        /* epilogue: fused-rcp activations (8 trans) */                             \
        {                                                                           \
            const float iv = cur[0][0], fv = cur[1][0];                             \
            const float gv = cur[2][0], ov = cur[3][0];                             \
            const float ei = exp2f(-C1 * iv);                                       \
            const float ef = exp2f(-C1 * fv);                                       \
            const float eg = exp2f(-2.0f * C1 * gv);                                \
            const float eo = exp2f(-C1 * ov);                                       \
            const float sf = rcp_f(1.0f + ef);                                      \
            const float itg = (1.0f - eg) * rcp_f((1.0f + ei) * (1.0f + eg));       \
            const float cc = __builtin_fmaf(sf, cst, itg);                          \
            cst = cc;                                                               \
            const float ec = exp2f(-2.0f * C1 * cc);                                \
            const float hv = (1.0f - ec) * rcp_f((1.0f + eo) * (1.0f + ec));        \
            hlast = hv;                                                             \
            *(short*)(smem + ((P) ^ 1) * 4096 + wboff) = f2bf(hv);                  \
        }                                                                           \
        __syncthreads();                                                            \
    }

#pragma unroll 1
    for (int tg = 0; tg < T; tg += 4) {
        // group top: 4 MFMAs produce xproj(+bias) for steps tg..tg+3 (h-independent);
        // prefetch next group's x.
        f32x4 acc4[4];
#pragma unroll
        for (int tt = 0; tt < 4; ++tt)
            acc4[tt] = MFMA_B16(xgC, Bx[tt], biasv[tt]);
        xgC = xgN;
        xgN = loadxg((tg + 8 < T) ? (tg + 8) : (T - 4));
        STEP(0, tg + 0, 0)
        STEP(1, tg + 1, 1)
        STEP(0, tg + 2, 2)
        STEP(1, tg + 3, 3)
    }
#undef STEP

    // ---- tail pred partial: t = T-1 uses h_{T-1}, sitting in buffer 0 ----
    {
        s16x8 Aft = *(const s16x8*)(smem + pkt * 1024 + L * 16);
        f32x4 pacc = MFMA_B16(Aft, Bp1, z4);
        if (col == 0)
            *(float*)(smem + PRED_OFF + pkt * 8192 + ((quad << 9) + (T - 1)) * 4) =
                pacc[0];
    }
    __syncthreads();

    // ---- flush pred stage -> global: sum 4 kt-partials + bias ----
#pragma unroll
    for (int e = tid; e < 4 * T; e += 512) {
        const int b = e >> 9, t = e & (T - 1);
        float s = bo;
#pragma unroll
        for (int kt = 0; kt < 4; ++kt)
            s += *(const float*)(smem + PRED_OFF + kt * 8192 + e * 4);
        out[((size_t)(bgrp * 4 + b) * T + t) * N + n] = s;
    }

    // ---- final hT, cT ----
    {
        const int bglob = bgrp * 4 + quad;
        const int j = w * 16 + col;
        out[HT_OFF + ((size_t)n * B + bglob) * H + j] = hlast;
        out[CT_OFF + ((size_t)n * B + bglob) * H + j] = cst;
    }
}

extern "C" void kernel_launch(void* const* d_in, const int* in_sizes, int n_in,
                              void* d_out, int out_size, void* d_ws, size_t ws_size,
                              hipStream_t stream) {
    const float* X     = (const float*)d_in[0];
    const float* W_ih  = (const float*)d_in[1];
    const float* W_hh  = (const float*)d_in[2];
    const float* b_ih  = (const float*)d_in[3];
    const float* b_hh  = (const float*)d_in[4];
    const float* W_out = (const float*)d_in[5];
    const float* b_out = (const float*)d_in[6];
    float* out = (float*)d_out;

    const int xelems = 32 * 512 * 32;  // B*T*N
    const bool usebf = ws_size >= (size_t)xelems * sizeof(short);

    if (usebf) {
        short* Xb = (short*)d_ws;
        xcvt_kernel<<<dim3(xelems / 1024), dim3(256), 0, stream>>>(X, Xb, xelems);
        clstm_kernel<true><<<dim3(256), dim3(512), 0, stream>>>(
            X, Xb, W_ih, W_hh, b_ih, b_hh, W_out, b_out, out);
    } else {
        clstm_kernel<false><<<dim3(256), dim3(512), 0, stream>>>(
            X, nullptr, W_ih, W_hh, b_ih, b_hh, W_out, b_out, out);
    }
}

// Round 10
// 362.414 us; speedup vs baseline: 3.3909x; 3.3909x over previous
//
#include <hip/hip_runtime.h>
#include <hip/hip_bf16.h>

typedef __attribute__((ext_vector_type(8))) short s16x8;
typedef __attribute__((ext_vector_type(4))) float f32x4;

#define MFMA_B16(a, b, c) __builtin_amdgcn_mfma_f32_16x16x32_bf16((a), (b), (c), 0, 0, 0)

static __device__ __forceinline__ short f2bf(float f) {
    __hip_bfloat16 h = __float2bfloat16(f);
    return __builtin_bit_cast(short, h);
}
static __device__ __forceinline__ float rcp_f(float x) {
    return __builtin_amdgcn_rcpf(x);
}

// pre-pass: X fp32 -> bf16 in workspace
__global__ void xcvt_kernel(const float* __restrict__ X, short* __restrict__ Xb, int n) {
    int i = (blockIdx.x * 256 + threadIdx.x) * 4;
    if (i < n) {
        float4 v = *(const float4*)(X + i);
        short4 o;
        o.x = f2bf(v.x); o.y = f2bf(v.y); o.z = f2bf(v.z); o.w = f2bf(v.w);
        *(short4*)(Xb + i) = o;
    }
}

// Ensemble LSTM, batch-split-8: WG = (series n, 4 batches). 256 WGs = 256 CUs.
// R19 = R18's symmetric pred partials with the rule-#20 violation fixed. R18's 3.5x
// regression was NOT the theory: Af[pkt] (runtime wave-dependent index into an
// ext_vector array) demoted Af to scratch -> per-step scratch round-trip, VALUBusy
// 87%, 32ms cold dispatch. Fix: the pred A-fragment is loaded by its OWN ds_read at
// computed address rb + pkt*1024 + L*16 (pkt wave-uniform; +1 ds_read_b128/wave/step,
// LDS traffic proven off-path). Still: 1 pred MFMA per wave per step (kt=w&3, waves
// w/w+4 duplicate harmlessly), no rotating straggler, uniform barrier arrival.
// Partials in 4x8KB slabs; flush sums + bias (f32 reassoc ~1e-7 << 3.9e-3 tol).
// Journal:
//   R5/R6 x-pair packing     -> +15 us   R7 asm barrier -> +21 us
//   R8 LDS atomicAdd pred    -> +834 us  R10 acc ping-pong -> neutral
//   R11 masked compact LDS   -> +105 us  R12 bounds(512,4) -> +3200 us (spill)
//   R13 grid 512             -> 2x       R14 compact bcast h -> +11 us
//   R15 fused xcvt           -> neutral (gap = harness overhead)
//   R16 4-step-grouped xproj -> -6 us (355.7 best; MFMA issue NOT the bottleneck)
//   R17 depth-1 gate chains  -> +33 us (MFMA C->C is pipe-forwarded; VALU tree isn't)
//   R18 symmetric pred, Af[pkt] -> +873 us (rule #20: runtime-indexed reg array
//        -> scratch; theory untested)
template<bool BF16X>
__global__ __launch_bounds__(512, 2)
void clstm_kernel(const float* __restrict__ X,
                  const short* __restrict__ Xb,
                  const float* __restrict__ W_ih,
                  const float* __restrict__ W_hh,
                  const float* __restrict__ b_ih,
                  const float* __restrict__ b_hh,
                  const float* __restrict__ W_out,
                  const float* __restrict__ b_out,
                  float* __restrict__ out)
{
    constexpr int B = 32, T = 512, N = 32, H = 128, G = 512;  // G = 4H
    constexpr int HT_OFF = B * T * N;
    constexpr int CT_OFF = HT_OFF + N * B * H;
    constexpr int PRED_OFF = 8192;     // 4 x 8KB pred partial slabs
    constexpr float C1 = 1.4426950408889634f;   // log2(e)

    __shared__ __align__(16) unsigned char smem[8192 + 32768];

    const int tid  = threadIdx.x;
    const int w    = tid >> 6;   // wave 0..7
    const int L    = tid & 63;
    const int col  = L & 15;
    const int quad = L >> 4;
    const int n    = blockIdx.x & 31;   // series
    const int bgrp = blockIdx.x >> 5;   // batch group (4 batches)
    const int pkt  = w & 3;             // this wave's pred kt-partial (wave-uniform)

    // ---- loop-invariant weight fragments (fp32 -> bf16, once) ----
    s16x8 Bh[4][4];  // [gate tt][kt]
    s16x8 Bx[4];     // [gate tt]  k = input p 0..31
    f32x4 biasv[4];  // bias broadcast (group-top C operand)
#pragma unroll
    for (int tt = 0; tt < 4; ++tt) {
        const int g = (w + 8 * tt) * 16 + col;
        const float* whr = W_hh + ((size_t)n * G + g) * H + quad * 8;
#pragma unroll
        for (int kt = 0; kt < 4; ++kt) {
            const float* p = whr + kt * 32;
#pragma unroll
            for (int jj = 0; jj < 8; ++jj) Bh[tt][kt][jj] = f2bf(p[jj]);
        }
        const float* wir = W_ih + ((size_t)n * G + g) * N + quad * 8;
#pragma unroll
        for (int jj = 0; jj < 8; ++jj) Bx[tt][jj] = f2bf(wir[jj]);
        const float bb = b_ih[n * G + g] + b_hh[n * G + g];
        biasv[tt] = (f32x4){bb, bb, bb, bb};
    }

    // ---- pred tile: ONE kt-slice per wave; B col 0 = W_out slice ----
    s16x8 Bp1;
    const float bo = b_out[n];
    const f32x4 z4 = (f32x4){0.f, 0.f, 0.f, 0.f};
    {
        const float* wp = W_out + n * H + pkt * 32 + quad * 8;
#pragma unroll
        for (int jj = 0; jj < 8; ++jj)
            Bp1[jj] = (col == 0) ? f2bf(wp[jj]) : (short)0;
    }

    // ---- h writer offset: cell (batch=quad -> m=4*quad, j=w*16+col) ----
    int wboff;
    {
        const int j = w * 16 + col;
        wboff = (j >> 5) * 1024 + (((((j >> 3) & 3) << 4) | (quad << 2)) * 16) + (j & 7) * 2;
    }
    // pred A-fragment LDS offset (wave-uniform slice, per-lane row)
    const int proff = pkt * 1024 + L * 16;

    // ---- grouped x loader: ALL lanes; A row = 4*batch + tsub ----
    const int xb = bgrp * 4 + (col >> 2);
    const int ts = col & 3;
    const float* xp  = X + ((size_t)xb * T + ts) * N + quad * 8;
    const short* xbp = BF16X ? (Xb + ((size_t)xb * T + ts) * N + quad * 8) : nullptr;

    auto loadxg = [&](int tg) -> s16x8 {
        if constexpr (BF16X) {
            return *(const s16x8*)(xbp + (size_t)tg * N);
        } else {
            float4 lo = *(const float4*)(xp + (size_t)tg * N);
            float4 hi = *(const float4*)(xp + (size_t)tg * N + 4);
            s16x8 r;
            r[0] = f2bf(lo.x); r[1] = f2bf(lo.y); r[2] = f2bf(lo.z); r[3] = f2bf(lo.w);
            r[4] = f2bf(hi.x); r[5] = f2bf(hi.y); r[6] = f2bf(hi.z); r[7] = f2bf(hi.w);
            return r;
        }
    };

    // zero h frag dbuf (pad rows must stay 0); pred slabs fully written before read
    *(float4*)(smem + tid * 16) = make_float4(0.f, 0.f, 0.f, 0.f);

    float cst = 0.f, hlast = 0.f;

    // prologue: x for group 0 and prefetch for group 1
    s16x8 xgC = loadxg(0);
    s16x8 xgN = loadxg(4);

    __syncthreads();

// Per step: Af from LDS; C operand = splat of acc4[tt][J]; gates accumulate
// in the MFMA pipe (C->C forwarded, R17 lesson). Pred: 1 partial MFMA per wave,
// A-fragment via its own ds_read (no dynamic reg indexing - R18 lesson).
#define STEP(P, TCUR, J)                                                            \
    {                                                                               \
        const unsigned char* rb = smem + (P) * 4096;                                \
        s16x8 Af[4];                                                                \
        _Pragma("unroll")                                                           \
        for (int kt = 0; kt < 4; ++kt)                                              \
            Af[kt] = *(const s16x8*)(rb + kt * 1024 + L * 16);                      \
        s16x8 Afp = *(const s16x8*)(rb + proff);                                    \
        f32x4 cur[4];                                                               \
        _Pragma("unroll")                                                           \
        for (int tt = 0; tt < 4; ++tt) {                                            \
            const float a = acc4[tt][(J)];                                          \
            cur[tt] = (f32x4){a, a, a, a};                                          \
        }                                                                           \
        _Pragma("unroll")                                                           \
        for (int kt = 0; kt < 4; ++kt) {                                            \
            _Pragma("unroll")                                                       \
            for (int tt = 0; tt < 4; ++tt)                                          \
                cur[tt] = MFMA_B16(Af[kt], Bh[tt][kt], cur[tt]);                    \
        }                                                                           \
        {                                                                           \
            f32x4 pacc = MFMA_B16(Afp, Bp1, z4);                                    \
            if ((TCUR) > 0 && col == 0)                                             \
                *(float*)(smem + PRED_OFF + pkt * 8192 +                            \
                          ((quad << 9) + (TCUR) - 1) * 4) = pacc[0];                \
        }                                                                           \
        /* epilogue: fused-rcp activations (8 trans) */                             \
        {                                                                           \
            const float iv = cur[0][0], fv = cur[1][0];                             \
            const float gv = cur[2][0], ov = cur[3][0];                             \
            const float ei = exp2f(-C1 * iv);                                       \
            const float ef = exp2f(-C1 * fv);                                       \
            const float eg = exp2f(-2.0f * C1 * gv);                                \
            const float eo = exp2f(-C1 * ov);                                       \
            const float sf = rcp_f(1.0f + ef);                                      \
            const float itg = (1.0f - eg) * rcp_f((1.0f + ei) * (1.0f + eg));       \
            const float cc = __builtin_fmaf(sf, cst, itg);                          \
            cst = cc;                                                               \
            const float ec = exp2f(-2.0f * C1 * cc);                                \
            const float hv = (1.0f - ec) * rcp_f((1.0f + eo) * (1.0f + ec));        \
            hlast = hv;                                                             \
            *(short*)(smem + ((P) ^ 1) * 4096 + wboff) = f2bf(hv);                  \
        }                                                                           \
        __syncthreads();                                                            \
    }

#pragma unroll 1
    for (int tg = 0; tg < T; tg += 4) {
        // group top: 4 MFMAs produce xproj(+bias) for steps tg..tg+3 (h-independent);
        // prefetch next group's x.
        f32x4 acc4[4];
#pragma unroll
        for (int tt = 0; tt < 4; ++tt)
            acc4[tt] = MFMA_B16(xgC, Bx[tt], biasv[tt]);
        xgC = xgN;
        xgN = loadxg((tg + 8 < T) ? (tg + 8) : (T - 4));
        STEP(0, tg + 0, 0)
        STEP(1, tg + 1, 1)
        STEP(0, tg + 2, 2)
        STEP(1, tg + 3, 3)
    }
#undef STEP

    // ---- tail pred partial: t = T-1 uses h_{T-1}, sitting in buffer 0 ----
    {
        s16x8 Aft = *(const s16x8*)(smem + proff);
        f32x4 pacc = MFMA_B16(Aft, Bp1, z4);
        if (col == 0)
            *(float*)(smem + PRED_OFF + pkt * 8192 + ((quad << 9) + (T - 1)) * 4) =
                pacc[0];
    }
    __syncthreads();

    // ---- flush pred stage -> global: sum 4 kt-partials + bias ----
#pragma unroll
    for (int e = tid; e < 4 * T; e += 512) {
        const int b = e >> 9, t = e & (T - 1);
        float s = bo;
#pragma unroll
        for (int kt = 0; kt < 4; ++kt)
            s += *(const float*)(smem + PRED_OFF + kt * 8192 + e * 4);
        out[((size_t)(bgrp * 4 + b) * T + t) * N + n] = s;
    }

    // ---- final hT, cT ----
    {
        const int bglob = bgrp * 4 + quad;
        const int j = w * 16 + col;
        out[HT_OFF + ((size_t)n * B + bglob) * H + j] = hlast;
        out[CT_OFF + ((size_t)n * B + bglob) * H + j] = cst;
    }
}

extern "C" void kernel_launch(void* const* d_in, const int* in_sizes, int n_in,
                              void* d_out, int out_size, void* d_ws, size_t ws_size,
                              hipStream_t stream) {
    const float* X     = (const float*)d_in[0];
    const float* W_ih  = (const float*)d_in[1];
    const float* W_hh  = (const float*)d_in[2];
    const float* b_ih  = (const float*)d_in[3];
    const float* b_hh  = (const float*)d_in[4];
    const float* W_out = (const float*)d_in[5];
    const float* b_out = (const float*)d_in[6];
    float* out = (float*)d_out;

    const int xelems = 32 * 512 * 32;  // B*T*N
    const bool usebf = ws_size >= (size_t)xelems * sizeof(short);

    if (usebf) {
        short* Xb = (short*)d_ws;
        xcvt_kernel<<<dim3(xelems / 1024), dim3(256), 0, stream>>>(X, Xb, xelems);
        clstm_kernel<true><<<dim3(256), dim3(512), 0, stream>>>(
            X, Xb, W_ih, W_hh, b_ih, b_hh, W_out, b_out, out);
    } else {
        clstm_kernel<false><<<dim3(256), dim3(512), 0, stream>>>(
            X, nullptr, W_ih, W_hh, b_ih, b_hh, W_out, b_out, out);
    }
}

// Round 12
// 342.470 us; speedup vs baseline: 3.5883x; 1.0582x over previous
//
#include <hip/hip_runtime.h>
#include <hip/hip_bf16.h>

typedef __attribute__((ext_vector_type(8))) short s16x8;
typedef __attribute__((ext_vector_type(4))) float f32x4;

#define MFMA_B16(a, b, c) __builtin_amdgcn_mfma_f32_16x16x32_bf16((a), (b), (c), 0, 0, 0)

static __device__ __forceinline__ short f2bf(float f) {
    __hip_bfloat16 h = __float2bfloat16(f);
    return __builtin_bit_cast(short, h);
}
static __device__ __forceinline__ float rcp_f(float x) {
    return __builtin_amdgcn_rcpf(x);
}

// pre-pass: X fp32 -> bf16 in workspace
__global__ void xcvt_kernel(const float* __restrict__ X, short* __restrict__ Xb, int n) {
    int i = (blockIdx.x * 256 + threadIdx.x) * 4;
    if (i < n) {
        float4 v = *(const float4*)(X + i);
        short4 o;
        o.x = f2bf(v.x); o.y = f2bf(v.y); o.z = f2bf(v.z); o.w = f2bf(v.w);
        *(short4*)(Xb + i) = o;
    }
}

// Ensemble LSTM, batch-split-8: WG = (series n, 4 batches). 256 WGs = 256 CUs.
// R21 = R20 resubmitted verbatim (R20's bench was an infra failure: "MI355X
// container failed twice" - no compile error, no counters; theory untested).
// R20 = VALU-issue cuts on the R16 base (355.7 best). Eliminated as critical path:
// MFMA issue (R16), LDS bytes/conflicts (R11/R14/R19), order (R10), C-chain depth
// (R17), occupancy (R12/R13), launches (R15), pred straggler (R19). Remaining
// addressable term: VALUBusy-MfmaUtil = 12.9% ~ 200cy/SIMD of scalar issue that
// delays MFMA issue in-order. Cuts:
//  (1) h written to ALL 4 rows of its quad-group (4x ds_write_b16): A-rows 4q+J all
//      hold batch q's h, so acc4[tt] is the MFMA C operand DIRECTLY (D=fresh regs)
//      and step tg+J's epilogue reads cur[tt][J] (row 4q+J has real h now, not
//      zero-pad). Kills all 16 splat v_movs. Compile-time indices only (R18 lesson).
//  (2) weights prescaled by the exp2 factor (-C1 for i/f/o, -2C1 for g) at load:
//      epilogue drops 4 pre-exp2 muls.
//  (3) c-state carried scaled (cc' = -2C1*cc): itg' = fma(2C1,eg,-2C1)*rcp(..),
//      cc' = fma(sf,cst',itg'), ec = exp2(cc'); one fixup mul for cT at the end.
// Journal:
//   R5/R6 x-pair packing   -> +15   R7 asm barrier -> +21   R8 LDS atomic -> +834
//   R10 ping-pong          -> 0     R11 masked LDS -> +105  R12 bounds(,4) -> spill
//   R13 grid 512           -> 2x    R14 compact h  -> +11   R15 fused xcvt -> 0
//   R16 grouped xproj      -> -6 (355.7 best; MFMA issue not the bottleneck)
//   R17 depth-1 chains     -> +33 (C->C forwarded in-pipe; VALU tree is not)
//   R18 Af[pkt] dyn index  -> +873 (rule #20: reg array -> scratch)
//   R19 symmetric pred     -> +7 (straggler theory refuted; revert to rotation)
template<bool BF16X>
__global__ __launch_bounds__(512, 2)
void clstm_kernel(const float* __restrict__ X,
                  const short* __restrict__ Xb,
                  const float* __restrict__ W_ih,
                  const float* __restrict__ W_hh,
                  const float* __restrict__ b_ih,
                  const float* __restrict__ b_hh,
                  const float* __restrict__ W_out,
                  const float* __restrict__ b_out,
                  float* __restrict__ out)
{
    constexpr int B = 32, T = 512, N = 32, H = 128, G = 512;  // G = 4H
    constexpr int HT_OFF = B * T * N;
    constexpr int CT_OFF = HT_OFF + N * B * H;
    constexpr int PRED_OFF = 8192;
    constexpr float C1  = 1.4426950408889634f;    // log2(e)
    constexpr float C2  = 2.8853900817779268f;    // 2*log2(e)
    constexpr float CFX = -0.34657359027997264f;  // -1/(2*log2(e)) : cc = cc'*CFX

    __shared__ __align__(16) unsigned char smem[16384];

    const int tid  = threadIdx.x;
    const int w    = tid >> 6;   // wave 0..7
    const int L    = tid & 63;
    const int col  = L & 15;
    const int quad = L >> 4;
    const int n    = blockIdx.x & 31;   // series
    const int bgrp = blockIdx.x >> 5;   // batch group (4 batches)

    // ---- loop-invariant weight fragments (fp32 -> bf16, once), PRESCALED ----
    s16x8 Bh[4][4];  // [gate tt][kt]   scaled by s_tt
    s16x8 Bx[4];     // [gate tt]       scaled by s_tt
    f32x4 biasv[4];  // bias broadcast, scaled by s_tt
#pragma unroll
    for (int tt = 0; tt < 4; ++tt) {
        const float s_tt = (tt == 2) ? -C2 : -C1;
        const int g = (w + 8 * tt) * 16 + col;
        const float* whr = W_hh + ((size_t)n * G + g) * H + quad * 8;
#pragma unroll
        for (int kt = 0; kt < 4; ++kt) {
            const float* p = whr + kt * 32;
#pragma unroll
            for (int jj = 0; jj < 8; ++jj) Bh[tt][kt][jj] = f2bf(s_tt * p[jj]);
        }
        const float* wir = W_ih + ((size_t)n * G + g) * N + quad * 8;
#pragma unroll
        for (int jj = 0; jj < 8; ++jj) Bx[tt][jj] = f2bf(s_tt * wir[jj]);
        const float bb = s_tt * (b_ih[n * G + g] + b_hh[n * G + g]);
        biasv[tt] = (f32x4){bb, bb, bb, bb};
    }

    // ---- pred tile: B col 0 = W_out, rotated across waves (UNSCALED path) ----
    s16x8 Bp[4];
    const float bo = b_out[n];
    const f32x4 bov = (f32x4){bo, bo, bo, bo};
#pragma unroll
    for (int kt = 0; kt < 4; ++kt) {
        const float* wp = W_out + n * H + kt * 32 + quad * 8;
#pragma unroll
        for (int jj = 0; jj < 8; ++jj)
            Bp[kt][jj] = (col == 0) ? f2bf(wp[jj]) : (short)0;
    }

    // ---- h writer offset: base row m=4*quad at (j-frag layout); +16/+32/+48 replicas ----
    int wboff;
    {
        const int j = w * 16 + col;
        wboff = (j >> 5) * 1024 + (((((j >> 3) & 3) << 4) | (quad << 2)) * 16) + (j & 7) * 2;
    }

    // ---- grouped x loader: ALL lanes; A row = 4*batch + tsub ----
    const int xb = bgrp * 4 + (col >> 2);
    const int ts = col & 3;
    const float* xp  = X + ((size_t)xb * T + ts) * N + quad * 8;
    const short* xbp = BF16X ? (Xb + ((size_t)xb * T + ts) * N + quad * 8) : nullptr;

    auto loadxg = [&](int tg) -> s16x8 {
        if constexpr (BF16X) {
            return *(const s16x8*)(xbp + (size_t)tg * N);
        } else {
            float4 lo = *(const float4*)(xp + (size_t)tg * N);
            float4 hi = *(const float4*)(xp + (size_t)tg * N + 4);
            s16x8 r;
            r[0] = f2bf(lo.x); r[1] = f2bf(lo.y); r[2] = f2bf(lo.z); r[3] = f2bf(lo.w);
            r[4] = f2bf(hi.x); r[5] = f2bf(hi.y); r[6] = f2bf(hi.z); r[7] = f2bf(hi.w);
            return r;
        }
    };

    // zero frag buffers (h_{-1}=0 for all rows) + pred stage
    *(float4*)(smem + tid * 16)        = make_float4(0.f, 0.f, 0.f, 0.f);
    *(float4*)(smem + 8192 + tid * 16) = make_float4(0.f, 0.f, 0.f, 0.f);

    float cstp = 0.f, hlast = 0.f;   // cstp = -2C1 * c  (scaled state)

    // prologue: x for group 0 and prefetch for group 1
    s16x8 xgC = loadxg(0);
    s16x8 xgN = loadxg(4);

    __syncthreads();

// Per step: Af from LDS; gate MFMA chain with C = acc4[tt] DIRECT (rows 4q+J hold
// real h via replication, so element [J] = gates for step tg+J). Epilogue reads
// cur[tt][J]; h replicated to 4 rows for the next step.
#define STEP(P, TCUR, J)                                                            \
    {                                                                               \
        const unsigned char* rb = smem + (P) * 4096;                                \
        s16x8 Af[4];                                                                \
        _Pragma("unroll")                                                           \
        for (int kt = 0; kt < 4; ++kt)                                              \
            Af[kt] = *(const s16x8*)(rb + kt * 1024 + L * 16);                      \
        f32x4 cur[4];                                                               \
        _Pragma("unroll")                                                           \
        for (int tt = 0; tt < 4; ++tt)                                              \
            cur[tt] = MFMA_B16(Af[0], Bh[tt][0], acc4[tt]);                         \
        _Pragma("unroll")                                                           \
        for (int kt = 1; kt < 4; ++kt) {                                            \
            _Pragma("unroll")                                                       \
            for (int tt = 0; tt < 4; ++tt)                                          \
                cur[tt] = MFMA_B16(Af[kt], Bh[tt][kt], cur[tt]);                    \
        }                                                                           \
        if (w == ((TCUR) & 7)) {                                                    \
            f32x4 pacc = bov;                                                       \
            _Pragma("unroll")                                                       \
            for (int kt = 0; kt < 4; ++kt)                                          \
                pacc = MFMA_B16(Af[kt], Bp[kt], pacc);                              \
            if ((TCUR) > 0 && col == 0)                                             \
                *(float*)(smem + PRED_OFF + ((quad << 9) + (TCUR) - 1) * 4) =       \
                    pacc[0];                                                        \
        }                                                                           \
        /* epilogue: gates pre-scaled -> direct exp2; scaled c-state */             \
        {                                                                           \
            const float iv = cur[0][(J)], fv = cur[1][(J)];                         \
            const float gv = cur[2][(J)], ov = cur[3][(J)];                         \
            const float ei = exp2f(iv);                                             \
            const float ef = exp2f(fv);                                             \
            const float eg = exp2f(gv);                                             \
            const float eo = exp2f(ov);                                             \
            const float sf  = rcp_f(1.0f + ef);                                     \
            const float tgm = __builtin_fmaf(C2, eg, -C2);                          \
            const float itgp = tgm * rcp_f((1.0f + ei) * (1.0f + eg));              \
            const float ccp = __builtin_fmaf(sf, cstp, itgp);                       \
            cstp = ccp;                                                             \
            const float ec = exp2f(ccp);                                            \
            const float hv = (1.0f - ec) * rcp_f((1.0f + eo) * (1.0f + ec));        \
            hlast = hv;                                                             \
            const short hb = f2bf(hv);                                              \
            unsigned char* wbp = smem + ((P) ^ 1) * 4096 + wboff;                   \
            *(short*)(wbp)      = hb;                                               \
            *(short*)(wbp + 16) = hb;                                               \
            *(short*)(wbp + 32) = hb;                                               \
            *(short*)(wbp + 48) = hb;                                               \
        }                                                                           \
        __syncthreads();                                                            \
    }

#pragma unroll 1
    for (int tg = 0; tg < T; tg += 4) {
        // group top: 4 MFMAs produce scaled xproj(+bias) for steps tg..tg+3;
        // prefetch next group's x.
        f32x4 acc4[4];
#pragma unroll
        for (int tt = 0; tt < 4; ++tt)
            acc4[tt] = MFMA_B16(xgC, Bx[tt], biasv[tt]);
        xgC = xgN;
        xgN = loadxg((tg + 8 < T) ? (tg + 8) : (T - 4));
        STEP(0, tg + 0, 0)
        STEP(1, tg + 1, 1)
        STEP(0, tg + 2, 2)
        STEP(1, tg + 3, 3)
    }
#undef STEP

    // ---- tail pred: t = T-1 uses h_{T-1}, sitting in buffer 0 ----
    if (w == 0) {
        f32x4 pacc = bov;
#pragma unroll
        for (int kt = 0; kt < 4; ++kt) {
            s16x8 Af = *(const s16x8*)(smem + kt * 1024 + L * 16);
            pacc = MFMA_B16(Af, Bp[kt], pacc);
        }
        if (col == 0)
            *(float*)(smem + PRED_OFF + ((quad << 9) + (T - 1)) * 4) = pacc[0];
    }
    __syncthreads();

    // ---- flush pred stage -> global ----
#pragma unroll
    for (int e = tid; e < 4 * T; e += 512) {
        const int b = e >> 9, t = e & (T - 1);
        out[((size_t)(bgrp * 4 + b) * T + t) * N + n] =
            *(const float*)(smem + PRED_OFF + e * 4);
    }

    // ---- final hT, cT (unscale c) ----
    {
        const int bglob = bgrp * 4 + quad;
        const int j = w * 16 + col;
        out[HT_OFF + ((size_t)n * B + bglob) * H + j] = hlast;
        out[CT_OFF + ((size_t)n * B + bglob) * H + j] = cstp * CFX;
    }
}

extern "C" void kernel_launch(void* const* d_in, const int* in_sizes, int n_in,
                              void* d_out, int out_size, void* d_ws, size_t ws_size,
                              hipStream_t stream) {
    const float* X     = (const float*)d_in[0];
    const float* W_ih  = (const float*)d_in[1];
    const float* W_hh  = (const float*)d_in[2];
    const float* b_ih  = (const float*)d_in[3];
    const float* b_hh  = (const float*)d_in[4];
    const float* W_out = (const float*)d_in[5];
    const float* b_out = (const float*)d_in[6];
    float* out = (float*)d_out;

    const int xelems = 32 * 512 * 32;  // B*T*N
    const bool usebf = ws_size >= (size_t)xelems * sizeof(short);

    if (usebf) {
        short* Xb = (short*)d_ws;
        xcvt_kernel<<<dim3(xelems / 1024), dim3(256), 0, stream>>>(X, Xb, xelems);
        clstm_kernel<true><<<dim3(256), dim3(512), 0, stream>>>(
            X, Xb, W_ih, W_hh, b_ih, b_hh, W_out, b_out, out);
    } else {
        clstm_kernel<false><<<dim3(256), dim3(512), 0, stream>>>(
            X, nullptr, W_ih, W_hh, b_ih, b_hh, W_out, b_out, out);
    }
}